// Round 5
// baseline (2562.692 us; speedup 1.0000x reference)
//
#include <hip/hip_runtime.h>
#include <stdint.h>

#define B_  256
#define T_  512
#define I_  256
#define H_  512
#define G3_ 1536

typedef _Float16 half8  __attribute__((ext_vector_type(8)));
typedef _Float16 half4v __attribute__((ext_vector_type(4)));
typedef __fp16   fp16x2 __attribute__((ext_vector_type(2)));   // cvt_pkrtz result type
typedef float    float4v __attribute__((ext_vector_type(4)));

__device__ __forceinline__ float sigmoid_f(float x) { return 1.f / (1.f + __expf(-x)); }
__device__ __forceinline__ float tanh_f(float x) {
  x = fminf(15.f, fmaxf(-15.f, x));
  float e = __expf(2.f * x);
  return (e - 1.f) / (e + 1.f);
}

__device__ __forceinline__ unsigned pk2(float lo, float hi) {
  fp16x2 p = __builtin_amdgcn_cvt_pkrtz(lo, hi);
  return *(unsigned*)&p;
}

// ---------------------------------------------------------------------------
// Kernel A v2: igates = (fp16)(x @ w_ih^T + b), 128x128 tile, K-chunks of 64.
// vs v1 (64x64): staged bytes/FLOP halved; cvt_pkrtz packs fp32->fp16 in 1 op
// per 2 elements (v1 burned ~6 VALU ops per float4 on scalar cvt).
// ---------------------------------------------------------------------------
__global__ __launch_bounds__(256) void igates_gemm(
    const float* __restrict__ x, const float* __restrict__ w_ih,
    const float* __restrict__ bias, _Float16* __restrict__ ig)
{
  __shared__ _Float16 Ash[128][72];
  __shared__ _Float16 Bsh[128][72];
  const int tid  = threadIdx.x;
  const int lane = tid & 63;
  const int wv   = tid >> 6;
  const int wm   = wv >> 1, wn = wv & 1;     // wave -> 64x64 quadrant
  const int n0   = blockIdx.x * 128;
  const int m0   = blockIdx.y * 128;         // m = t*256 + b
  const int cn   = lane & 15;
  const int rq   = lane >> 4;

  float4v acc[4][4];
  #pragma unroll
  for (int a = 0; a < 4; ++a)
    #pragma unroll
    for (int c = 0; c < 4; ++c) acc[a][c] = (float4v){0.f, 0.f, 0.f, 0.f};

  for (int kc = 0; kc < I_; kc += 64) {
    // stage A,B: each 128 rows x 64 K fp32 -> fp16. 8 float4/thread each.
    #pragma unroll
    for (int i = 0; i < 8; ++i) {
      int e   = tid + (i << 8);
      int row = e >> 4;
      int c4  = e & 15;
      int m   = m0 + row;
      int tt  = m >> 8, bb = m & 255;
      float4 va = *(const float4*)(x + ((size_t)bb * T_ + tt) * I_ + kc + (c4 << 2));
      uint2 ua; ua.x = pk2(va.x, va.y); ua.y = pk2(va.z, va.w);
      *(uint2*)&Ash[row][c4 << 2] = ua;
      float4 vb = *(const float4*)(w_ih + (size_t)(n0 + row) * I_ + kc + (c4 << 2));
      uint2 ub; ub.x = pk2(vb.x, vb.y); ub.y = pk2(vb.z, vb.w);
      *(uint2*)&Bsh[row][c4 << 2] = ub;
    }
    __syncthreads();
    #pragma unroll
    for (int ks = 0; ks < 2; ++ks) {
      int kk = (ks << 5) + (rq << 3);
      half8 af[4], bf[4];
      #pragma unroll
      for (int mt = 0; mt < 4; ++mt)
        af[mt] = *(const half8*)&Ash[(wm << 6) + (mt << 4) + cn][kk];
      #pragma unroll
      for (int nt = 0; nt < 4; ++nt)
        bf[nt] = *(const half8*)&Bsh[(wn << 6) + (nt << 4) + cn][kk];
      #pragma unroll
      for (int mt = 0; mt < 4; ++mt)
        #pragma unroll
        for (int nt = 0; nt < 4; ++nt)
          acc[mt][nt] = __builtin_amdgcn_mfma_f32_16x16x32_f16(af[mt], bf[nt], acc[mt][nt], 0, 0, 0);
    }
    __syncthreads();
  }
  // epilogue: C/D layout col = lane&15, row = rq*4 + r
  float bv[4];
  #pragma unroll
  for (int nt = 0; nt < 4; ++nt) bv[nt] = bias[n0 + (wn << 6) + (nt << 4) + cn];
  #pragma unroll
  for (int mt = 0; mt < 4; ++mt)
    #pragma unroll
    for (int nt = 0; nt < 4; ++nt) {
      int mrow = m0 + (wm << 6) + (mt << 4) + (rq << 2);
      int ncol = n0 + (wn << 6) + (nt << 4) + cn;
      #pragma unroll
      for (int r = 0; r < 4; ++r)
        ig[(size_t)(mrow + r) * G3_ + ncol] = (_Float16)(acc[mt][nt][r] + bv[nt]);
    }
}

// ---------------------------------------------------------------------------
// Kernel B: persistent GRU scan, v4 — tag-in-data protocol.
// h elements published as u32 = (step_tag << 16) | fp16_bits via relaxed
// agent-scope stores (write-through at the L3 coherence point). Consumers
// load u64 pairs and retry only stale (tag mismatch) elements.
// Removes per-step: producer s_waitcnt(0), flag store, flag L3 hop, and one
// barrier — round-3 evidence showed ~6000 of 7200 cyc/step was exactly this
// serialized 3-round-trip chain. One L3 round trip remains.
// Safety: consumer seeing tag t on ALL elements of buf[t&1] proves every peer
// issued its h(t) stores, which are data-dependent on that peer's h(t-1)
// loads — so overwriting buf[(t+1)&1] (which holds h(t-1)) is race-free.
// t=0 needs no special case: zeroed buf0 = (tag 0, h=0.0).
// ---------------------------------------------------------------------------
__global__ __launch_bounds__(256, 1) void gru_scan(
    const _Float16* __restrict__ ig, const float* __restrict__ w_hh,
    const float* __restrict__ b_n,
    uint32_t* __restrict__ hb0, uint32_t* __restrict__ hb1)
{
  __shared__ _Float16 h_lds[16][520];   // h(t): 16 batches x 512 cols (+8 pad)

  const int tid  = threadIdx.x;
  const int lane = tid & 63;
  const int wv   = tid >> 6;                 // wave 0..3
  const int blk  = blockIdx.x;
  // chain (b-group) WGs share blk%16 -> same XCD under %8 round-robin placement
  const int gb   = ((blk & 7) << 1) | ((blk >> 3) & 1);  // 0..15
  const int gs   = blk >> 4;                              // 0..7
  const int b0   = gb << 4;
  const int j0   = gs << 6;
  const int jw   = j0 + (wv << 4);           // first h-col of this wave
  const int cn   = lane & 15;
  const int rq   = lane >> 4;                // 0..3

  // --- one-time w_hh fragment load (resident in VGPR/AGPR unified file) ---
  // B-frag: lane holds W[jw+cn][k], k = ks*32 + rq*8 + i
  half8 wfrag[3][16];
  #pragma unroll
  for (int g = 0; g < 3; ++g) {
    const float* wrow = w_hh + (size_t)(g * H_ + jw + cn) * H_;
    #pragma unroll
    for (int ks = 0; ks < 16; ++ks) {
      int k = (ks << 5) + (rq << 3);
      half8 w;
      #pragma unroll
      for (int i = 0; i < 8; ++i) w[i] = (_Float16)wrow[k + i];
      wfrag[g][ks] = w;
    }
  }
  const float bnv = b_n[jw + cn];

  uint32_t* bufs[2] = { hb0, hb1 };

  for (int t = 0; t < T_; ++t) {
    // ---- first-pass h(t) loads: 16 u64/thread covering 16 rows x 512 cols.
    // u64 i covers cols {2c,2c+1}; linear idx = row*256 + cpair = i*256 + tid.
    const uint64_t* src = (const uint64_t*)bufs[t & 1] + ((size_t)b0 << 8);
    uint64_t hv[16];
    #pragma unroll
    for (int i = 0; i < 16; ++i)
      hv[i] = __hip_atomic_load(src + (i << 8) + tid,
                                __ATOMIC_RELAXED, __HIP_MEMORY_SCOPE_AGENT);

    // ig prefetch (in flight while we tag-check h)
    float igv[3][4];
    {
      const _Float16* igb =
          ig + (size_t)(t * B_ + b0 + (rq << 2)) * G3_ + jw + cn;
      #pragma unroll
      for (int g = 0; g < 3; ++g)
        #pragma unroll
        for (int r = 0; r < 4; ++r)
          igv[g][r] = (float)igb[(size_t)r * G3_ + g * H_];
    }

    // ---- tag check + retry only stale elements
    const uint64_t patt = ((uint64_t)(uint32_t)t << 16) | ((uint64_t)(uint32_t)t << 48);
    uint32_t pend = 0;
    #pragma unroll
    for (int i = 0; i < 16; ++i)
      if ((hv[i] & 0xFFFF0000FFFF0000ULL) != patt) pend |= (1u << i);
    while (pend) {
      #pragma unroll
      for (int i = 0; i < 16; ++i)
        if (pend & (1u << i))
          hv[i] = __hip_atomic_load(src + (i << 8) + tid,
                                    __ATOMIC_RELAXED, __HIP_MEMORY_SCOPE_AGENT);
      #pragma unroll
      for (int i = 0; i < 16; ++i)
        if ((pend & (1u << i)) && (hv[i] & 0xFFFF0000FFFF0000ULL) == patt)
          pend &= ~(1u << i);
    }

    // ---- unpack (strip tags) into LDS
    #pragma unroll
    for (int i = 0; i < 16; ++i) {
      int idx = (i << 8) + tid;
      int row = idx >> 8, cp = idx & 255;
      uint32_t pk = (uint32_t)(hv[i] & 0xFFFF) | ((uint32_t)(hv[i] >> 32) << 16);
      *(uint32_t*)&h_lds[row][cp << 1] = pk;
    }
    __syncthreads();

    // ---- MFMA: 3 gates x 16 K-chunks; even/odd split halves the dep chain
    float4v acc[3][2];
    #pragma unroll
    for (int g = 0; g < 3; ++g) {
      acc[g][0] = (float4v){0.f, 0.f, 0.f, 0.f};
      acc[g][1] = (float4v){0.f, 0.f, 0.f, 0.f};
    }
    #pragma unroll
    for (int ks = 0; ks < 16; ++ks) {
      half8 a = *(const half8*)&h_lds[cn][(ks << 5) + (rq << 3)];
      int p = ks & 1;
      acc[0][p] = __builtin_amdgcn_mfma_f32_16x16x32_f16(a, wfrag[0][ks], acc[0][p], 0, 0, 0);
      acc[1][p] = __builtin_amdgcn_mfma_f32_16x16x32_f16(a, wfrag[1][ks], acc[1][p], 0, 0, 0);
      acc[2][p] = __builtin_amdgcn_mfma_f32_16x16x32_f16(a, wfrag[2][ks], acc[2][p], 0, 0, 0);
    }

    // ---- epilogue: lane owns (b = rq*4+r, col = jw+cn); direct tagged stores
    uint32_t* dst = bufs[(t + 1) & 1];
    const uint32_t tagbits = (uint32_t)(t + 1) << 16;
    #pragma unroll
    for (int r = 0; r < 4; ++r) {
      float rg = sigmoid_f(igv[0][r] + acc[0][0][r] + acc[0][1][r]);
      float zg = sigmoid_f(igv[1][r] + acc[1][0][r] + acc[1][1][r]);
      float nv = tanh_f(igv[2][r] + rg * (acc[2][0][r] + acc[2][1][r] + bnv));
      float hp = (float)h_lds[(rq << 2) + r][jw + cn];
      _Float16 hh = (_Float16)(nv + zg * (hp - nv));
      uint32_t val = tagbits | (uint32_t)*(uint16_t*)&hh;
      __hip_atomic_store(dst + (((size_t)(b0 + (rq << 2) + r)) << 9) + jw + cn,
                         val, __ATOMIC_RELAXED, __HIP_MEMORY_SCOPE_AGENT);
    }
    __syncthreads();   // all h_lds reads done before next iter overwrites it
  }
}

// ---------------------------------------------------------------------------
// Kernel C: e[b] = h_T[b] . w_proj + b_proj.  h_T tagged-u32 in hb0 (T even).
// ---------------------------------------------------------------------------
__global__ __launch_bounds__(64) void proj_kernel(
    const uint32_t* __restrict__ h, const float* __restrict__ w_proj,
    const float* __restrict__ b_proj, float* __restrict__ out)
{
  int b = blockIdx.x;
  int lane = threadIdx.x;
  float s = 0.f;
  #pragma unroll
  for (int i = 0; i < 8; ++i) {
    int j = lane + (i << 6);
    uint16_t u = (uint16_t)(h[((size_t)b << 9) + j] & 0xFFFF);
    s += (float)*(_Float16*)&u * w_proj[j];
  }
  #pragma unroll
  for (int off = 32; off > 0; off >>= 1) s += __shfl_down(s, off, 64);
  if (lane == 0) out[b] = s + b_proj[0];
}

// ---------------------------------------------------------------------------
extern "C" void kernel_launch(void* const* d_in, const int* in_sizes, int n_in,
                              void* d_out, int out_size, void* d_ws, size_t ws_size,
                              hipStream_t stream) {
  const float* x      = (const float*)d_in[0];
  const float* w_ih   = (const float*)d_in[1];
  const float* w_hh   = (const float*)d_in[2];
  const float* bias   = (const float*)d_in[3];
  const float* b_n    = (const float*)d_in[4];
  const float* w_proj = (const float*)d_in[5];
  const float* b_proj = (const float*)d_in[6];
  float* out = (float*)d_out;

  char* ws = (char*)d_ws;
  const size_t IG_BYTES = (size_t)T_ * B_ * G3_ * sizeof(_Float16); // 402,653,184
  const size_t HB_BYTES = (size_t)B_ * H_ * sizeof(uint32_t);       // 524,288
  _Float16* igbuf = (_Float16*)ws;
  uint32_t* hbuf0 = (uint32_t*)(ws + IG_BYTES);
  uint32_t* hbuf1 = (uint32_t*)(ws + IG_BYTES + HB_BYTES);

  // zero buf0 => (tag=0, h=0.0) for t=0; buf1's poison never matches a tag
  (void)hipMemsetAsync(ws + IG_BYTES, 0, HB_BYTES, stream);

  dim3 gridA(G3_ / 128, (T_ * B_) / 128);   // (12, 1024)
  igates_gemm<<<gridA, 256, 0, stream>>>(x, w_ih, bias, igbuf);
  gru_scan<<<128, 256, 0, stream>>>(igbuf, w_hh, b_n, hbuf0, hbuf1);
  proj_kernel<<<B_, 64, 0, stream>>>(hbuf0, w_proj, b_proj, out);
}